// Round 6
// baseline (195.568 us; speedup 1.0000x reference)
//
#include <hip/hip_runtime.h>

#define B_ 4
#define L_ 4096
#define D_ 1024
#define N_ 64

typedef _Float16 f16;
typedef __attribute__((ext_vector_type(8))) _Float16 half8;
typedef __attribute__((ext_vector_type(4))) float f32x4;

__device__ __forceinline__ float softplus_f(float x) {
    return fmaxf(x, 0.0f) + log1pf(__expf(-fabsf(x)));
}

__device__ __forceinline__ float tanh_f(float x) {
    float xc = fminf(fmaxf(x, -15.0f), 15.0f);
    float e = __expf(2.0f * xc);
    return (e - 1.0f) / (e + 1.0f);
}

// raw workgroup barrier: no vmcnt(0)/lgkmcnt(0) drain (unlike __syncthreads).
__device__ __forceinline__ void barrier_raw() {
    asm volatile("" ::: "memory");
    __builtin_amdgcn_s_barrier();
    asm volatile("" ::: "memory");
}

// ---------------------------------------------------------------------------
// Prep: WT [192][1024] f16 (rows 0-127 = Wp cols, 128-191 = Ws cols);
// WoT [1024][64] f16.  v2: swapped index roles -> lane-consecutive COLUMN
// => coalesced reads (256B/instr); writes scattered uint4 (fire-and-forget).
// ---------------------------------------------------------------------------
__global__ __launch_bounds__(256) void k_prepw(
    const float* __restrict__ Wp, const float* __restrict__ Ws,
    const float* __restrict__ Wo, f16* __restrict__ WT, f16* __restrict__ WoT)
{
    int gid = blockIdx.x * 256 + threadIdx.x;
    if (gid < 16384) {                        // Wp: [1024][128]
        int c = gid & 127, kg = gid >> 7;     // kg = 0..127 (8 rows each)
        f16 h[8];
        #pragma unroll
        for (int j = 0; j < 8; j++)
            h[j] = (f16)Wp[(size_t)(kg * 8 + j) * 128 + c];
        *(uint4*)&WT[(size_t)c * 1024 + kg * 8] = *(uint4*)h;
    } else if (gid < 24576) {                 // Ws: [1024][64]
        int idx = gid - 16384;
        int c = idx & 63, kg = idx >> 6;      // kg = 0..127
        f16 h[8];
        #pragma unroll
        for (int j = 0; j < 8; j++)
            h[j] = (f16)Ws[(size_t)(kg * 8 + j) * 64 + c];
        *(uint4*)&WT[(size_t)(128 + c) * 1024 + kg * 8] = *(uint4*)h;
    } else {                                  // Wo: [64][1024] -> WoT [1024][64]
        int idx = gid - 24576;                // 0..8191
        int d = idx & 1023, ng = idx >> 10;   // ng = 0..7
        f16 h[8];
        #pragma unroll
        for (int j = 0; j < 8; j++)
            h[j] = (f16)Wo[(size_t)(ng * 8 + j) * D_ + d];
        *(uint4*)&WoT[(size_t)d * 64 + ng * 8] = *(uint4*)h;
    }
}

// ---------------------------------------------------------------------------
// Fused frontend v7: 16 tok/block, 1024 blocks, 4 blocks/CU.
// 256-dim chunks -> only 4 latency links/block (was 16).  Per chunk:
//   raw barrier (a)  [no vmcnt drain -> x prefetch stays in flight]
//   xh write (vmcnt for rA auto-inserted at first use)
//   __syncthreads (b) ; conv once into ch ; __syncthreads (c)
//   afA (12 L2 loads) -> 12 MFMA -> afB -> LDX(c+1) -> 12 MFMA
// LDX issued after ALL af loads so no MFMA vmcnt wait drains the prefetch
// (vmcnt retires in issue order).  LDS 39.5KB: xh[20][264] ch[16][264]
// cwS[5][1024]f32; sE aliases for epilogue.  Stride 264 f16 = 132 dw
// (== 4 mod 32): b128 frag reads land 2 lanes/bank = conflict-free.
// ---------------------------------------------------------------------------
#define CHD 256
#define NCH 4
#define XS  264
__global__ __launch_bounds__(256, 4) void k_frontend(
    const float* __restrict__ x, const float* __restrict__ conv_w,
    const float* __restrict__ conv_b, const f16* __restrict__ WT,
    const float* __restrict__ bp, const float* __restrict__ bs,
    const float* __restrict__ dt_log,
    f16* __restrict__ zT, f16* __restrict__ cT)
{
    __shared__ __align__(16) char smem[39488];
    f16*   xh  = (f16*)smem;                  // [20][XS]  10560 B
    f16*   ch  = (f16*)(smem + 10560);        // [16][XS]   8448 B
    float* cwS = (float*)(smem + 19008);      // [5][1024] 20480 B
    float* sE  = (float*)smem;                // epilogue alias (13056 B)

    const int tid = threadIdx.x;
    const int w = tid >> 6, lane = tid & 63;
    const int r = lane & 15, q = lane >> 4;
    const int T0 = blockIdx.x * 16;
    const int bb = T0 >> 12;
    const int l0 = T0 & (L_ - 1);
    const int cw0 = w * 48;

    f32x4 acc[3] = {};
    float4 rA[5];

    // stage conv weights + bias into LDS once (visible after barrier (b) c=0)
    #pragma unroll
    for (int i = 0; i < 5; i++) {
        int idx = tid + 256 * i;
        float4 v = (idx < 1024) ? ((const float4*)conv_w)[idx]
                                : ((const float4*)conv_b)[idx - 1024];
        ((float4*)cwS)[idx] = v;
    }

    // staging: 20 rows x 64 float4 groups = 1280 slots = exactly 5/thread
    #define LDX(c0)                                                          \
        {                                                                    \
            _Pragma("unroll")                                                \
            for (int s = 0; s < 5; s++) {                                    \
                int idx = tid + 256 * s;                                     \
                int row = idx >> 6, g = idx & 63;                            \
                int l = l0 + row - 4;                                        \
                float4 v = make_float4(0.f, 0.f, 0.f, 0.f);                  \
                if (l >= 0)                                                  \
                    v = *(const float4*)&x[((size_t)(bb * L_ + l)) * D_      \
                                           + (c0) + g * 4];                  \
                rA[s] = v;                                                   \
            }                                                                \
        }

    LDX(0);
    for (int c = 0; c < NCH; c++) {
        barrier_raw();     // (a): arrival implies all prior LDS reads done
        #pragma unroll
        for (int s = 0; s < 5; s++) {
            int idx = tid + 256 * s;
            int row = idx >> 6, g = idx & 63;
            f16 h[4] = {(f16)rA[s].x, (f16)rA[s].y, (f16)rA[s].z, (f16)rA[s].w};
            *(uint2*)&xh[row * XS + g * 4] = *(uint2*)h;
        }
        __syncthreads();   // (b): xh (and cwS at c==0) visible

        const int k0 = c * CHD;

        // conv once: thread = 4 tokens ((tid>>6)*4..) x 4 dims ((tid&63)*4..)
        {
            const int r0 = (tid >> 6) * 4;
            const int d4 = (tid & 63) * 4;
            const int dg = k0 + d4;
            f32x4 w0 = *(const f32x4*)&cwS[dg];
            f32x4 w1 = *(const f32x4*)&cwS[1024 + dg];
            f32x4 w2 = *(const f32x4*)&cwS[2048 + dg];
            f32x4 w3 = *(const f32x4*)&cwS[3072 + dg];
            f32x4 cb = *(const f32x4*)&cwS[4096 + dg];
            uint2 win[4];
            win[0] = *(const uint2*)&xh[(r0 + 1) * XS + d4];
            win[1] = *(const uint2*)&xh[(r0 + 2) * XS + d4];
            win[2] = *(const uint2*)&xh[(r0 + 3) * XS + d4];
            #pragma unroll
            for (int t = 0; t < 4; t++) {
                win[3] = *(const uint2*)&xh[(r0 + t + 4) * XS + d4];
                const f16* x0 = (const f16*)&win[0];
                const f16* x1 = (const f16*)&win[1];
                const f16* x2 = (const f16*)&win[2];
                const f16* x3 = (const f16*)&win[3];
                f16 ho[4];
                #pragma unroll
                for (int j = 0; j < 4; j++) {
                    float s = cb[j];
                    s = fmaf(w0[j], (float)x0[j], s);
                    s = fmaf(w1[j], (float)x1[j], s);
                    s = fmaf(w2[j], (float)x2[j], s);
                    s = fmaf(w3[j], (float)x3[j], s);
                    ho[j] = (f16)s;
                }
                *(uint2*)&ch[(r0 + t) * XS + d4] = *(uint2*)ho;
                win[0] = win[1]; win[1] = win[2]; win[2] = win[3];
            }
        }
        __syncthreads();   // (c): ch ready

        const bool needC = (cw0 < 128);          // w 0,1,2
        const bool needR = (cw0 + 32 >= 128);    // w 2,3
        const bool uc0 = (cw0      < 128);
        const bool uc1 = (cw0 + 16 < 128);
        const bool uc2 = (cw0 + 32 < 128);

        // first half: afA (12 L2 loads) then 12 MFMA
        half8 afA[4][3];
        #pragma unroll
        for (int ks = 0; ks < 4; ks++) {
            const int kk = k0 + ks * 32 + q * 8;
            afA[ks][0] = *(const half8*)&WT[(size_t)(cw0 +      r) * 1024 + kk];
            afA[ks][1] = *(const half8*)&WT[(size_t)(cw0 + 16 + r) * 1024 + kk];
            afA[ks][2] = *(const half8*)&WT[(size_t)(cw0 + 32 + r) * 1024 + kk];
        }
        #pragma unroll
        for (int ks = 0; ks < 4; ks++) {
            const int kl = ks * 32 + q * 8;
            half8 bc = {}, br = {};
            if (needC) bc = *(const half8*)&ch[r * XS + kl];
            if (needR) br = *(const half8*)&xh[(r + 4) * XS + kl];
            acc[0] = __builtin_amdgcn_mfma_f32_16x16x32_f16(afA[ks][0], uc0 ? bc : br, acc[0], 0, 0, 0);
            acc[1] = __builtin_amdgcn_mfma_f32_16x16x32_f16(afA[ks][1], uc1 ? bc : br, acc[1], 0, 0, 0);
            acc[2] = __builtin_amdgcn_mfma_f32_16x16x32_f16(afA[ks][2], uc2 ? bc : br, acc[2], 0, 0, 0);
        }
        // second half: afB loads, then x prefetch (LAST among loads), 12 MFMA
        half8 afB[4][3];
        #pragma unroll
        for (int ks = 0; ks < 4; ks++) {
            const int kk = k0 + 128 + ks * 32 + q * 8;
            afB[ks][0] = *(const half8*)&WT[(size_t)(cw0 +      r) * 1024 + kk];
            afB[ks][1] = *(const half8*)&WT[(size_t)(cw0 + 16 + r) * 1024 + kk];
            afB[ks][2] = *(const half8*)&WT[(size_t)(cw0 + 32 + r) * 1024 + kk];
        }
        if (c < NCH - 1) LDX((c + 1) * CHD);
        #pragma unroll
        for (int ks = 0; ks < 4; ks++) {
            const int kl = 128 + ks * 32 + q * 8;
            half8 bc = {}, br = {};
            if (needC) bc = *(const half8*)&ch[r * XS + kl];
            if (needR) br = *(const half8*)&xh[(r + 4) * XS + kl];
            acc[0] = __builtin_amdgcn_mfma_f32_16x16x32_f16(afB[ks][0], uc0 ? bc : br, acc[0], 0, 0, 0);
            acc[1] = __builtin_amdgcn_mfma_f32_16x16x32_f16(afB[ks][1], uc1 ? bc : br, acc[1], 0, 0, 0);
            acc[2] = __builtin_amdgcn_mfma_f32_16x16x32_f16(afB[ks][2], uc2 ? bc : br, acc[2], 0, 0, 0);
        }
    }

    // --- epilogue: bias + activation -> sE (aliases xh/ch/cwS) ---
    float* sB = sE;
    float* sC = sE + 16 * 68;
    float* sU = sE + 2 * 16 * 68;
    __syncthreads();   // all LDS reads of xh/ch done before overwrite
    #pragma unroll
    for (int mf = 0; mf < 3; mf++) {
        const int cb4 = cw0 + mf * 16 + q * 4;
        const int seg = cb4 >> 6;          // 0=Bt 1=Ct 2=u (frag-uniform)
        const int cl = cb4 & 63;
        const float4 bb4 = (seg == 2) ? *(const float4*)&bs[cl]
                                      : *(const float4*)&bp[cb4];
        float* dst = (seg == 0) ? sB : (seg == 1 ? sC : sU);
        float v0 = acc[mf][0] + bb4.x;
        float v1 = acc[mf][1] + bb4.y;
        float v2 = acc[mf][2] + bb4.z;
        float v3 = acc[mf][3] + bb4.w;
        if (seg == 0) {
            v0 = softplus_f(v0); v1 = softplus_f(v1);
            v2 = softplus_f(v2); v3 = softplus_f(v3);
        } else if (seg == 1) {
            v0 = tanh_f(v0); v1 = tanh_f(v1);
            v2 = tanh_f(v2); v3 = tanh_f(v3);
        }
        float4 vv = {v0, v1, v2, v3};
        *(float4*)&dst[r * 68 + cl] = vv;
    }
    __syncthreads();

    // --- fused combine: z = dt[n]*Bt*u, store zT/cT n-major ---
    {
        const int n = tid >> 2, tg = tid & 3;
        const float dtv = softplus_f(dt_log[n]);
        f16 hz[4], hc[4];
        #pragma unroll
        for (int j = 0; j < 4; j++) {
            const int t = tg * 4 + j;
            hz[j] = (f16)(dtv * sB[t * 68 + n] * sU[t * 68 + n]);
            hc[j] = (f16)sC[t * 68 + n];
        }
        size_t o = ((size_t)(bb * N_ + n)) * L_ + l0 + tg * 4;
        *(uint2*)&zT[o] = *(uint2*)hz;
        *(uint2*)&cT[o] = *(uint2*)hc;
    }
    #undef LDX
}
#undef CHD
#undef NCH
#undef XS

// ---------------------------------------------------------------------------
// Scan v2: 256 threads per (b,n) chain.  Thread t owns elems [16t,16t+16);
// serial 16-fma local reduce -> 64-lane shfl affine scan -> cross-wave
// stitch via LDS -> apply.  +i>>4 swizzle avoids 32-way bank conflicts.
// ---------------------------------------------------------------------------
#define ZI(i) ((i) + ((i) >> 4))
__global__ __launch_bounds__(256) void k_scan(
    const f16* __restrict__ zT, const f16* __restrict__ cT,
    const float* __restrict__ A_log, const float* __restrict__ dt_log,
    f16* __restrict__ yH)
{
    __shared__ float zs[4352];
    __shared__ float cs[4352];
    __shared__ float sA[4], sB[4];
    const int bn = blockIdx.x;
    const int n = bn & (N_ - 1);
    const int tid = threadIdx.x;
    const int lane = tid & 63, w = tid >> 6;
    const f16* zp = zT + (size_t)bn * L_;
    const f16* cp = cT + (size_t)bn * L_;

    #pragma unroll
    for (int it = 0; it < 2; it++) {
        int i = tid * 8 + it * 2048;
        uint4 rz = *(const uint4*)(zp + i);
        uint4 rc = *(const uint4*)(cp + i);
        const f16* hz = (const f16*)&rz;
        const f16* hc = (const f16*)&rc;
        #pragma unroll
        for (int k = 0; k < 8; k++) {
            zs[ZI(i + k)] = (float)hz[k];
            cs[ZI(i + k)] = (float)hc[k];
        }
    }
    __syncthreads();

    float dtv = softplus_f(dt_log[n]);
    float Av = -softplus_f(A_log[n]);
    float dec = fmaf(dtv, Av, 1.0f);

    const int base = tid * 17;           // ZI(tid*16)
    float s = 0.0f;
    #pragma unroll
    for (int j = 0; j < 16; j++) s = fmaf(dec, s, zs[base + j]);

    float d2 = dec * dec, d4 = d2 * d2, d8 = d4 * d4, d16 = d8 * d8;

    float Ag = d16, Bg = s;
    #pragma unroll
    for (int off = 1; off < 64; off <<= 1) {
        float Ap = __shfl_up(Ag, off);
        float Bp = __shfl_up(Bg, off);
        if (lane >= off) { Bg = fmaf(Ag, Bp, Bg); Ag *= Ap; }
    }
    if (lane == 63) { sA[w] = Ag; sB[w] = Bg; }
    __syncthreads();

    float Bc = 0.0f;                      // carry entering this wave
    for (int i = 0; i < w; i++) Bc = fmaf(sA[i], Bc, sB[i]);
    float Ae = __shfl_up(Ag, 1);          // exclusive within wave
    float Be = __shfl_up(Bg, 1);
    if (lane == 0) { Ae = 1.0f; Be = 0.0f; }
    float carry = fmaf(Ae, Bc, Be);       // state entering this thread

    float st = carry;
    #pragma unroll
    for (int j = 0; j < 16; j++) {
        st = fmaf(dec, st, zs[base + j]);
        zs[base + j] = cs[base + j] * st;
    }
    __syncthreads();

    f16* yp = yH + (size_t)bn * L_;
    #pragma unroll
    for (int it = 0; it < 2; it++) {
        int i = tid * 8 + it * 2048;
        f16 h[8];
        #pragma unroll
        for (int k = 0; k < 8; k++) h[k] = (f16)zs[ZI(i + k)];
        *(uint4*)&yp[i] = *(uint4*)h;
    }
}
#undef ZI

// ---------------------------------------------------------------------------
// Out GEMM: out[t][d] = y[t][:] @ Wo[:,d] + bo.  A = WoT (m=d), B = y (n=tok)
// -> D rows are d -> float4 coalesced stores.  Block 256 thr: 64 tok x 128 d,
// wave = 32 d x 64 tok.  Grid (256, 8) = 2048 blocks = 8/CU.
// ---------------------------------------------------------------------------
__global__ __launch_bounds__(256) void k_out(
    const f16* __restrict__ yH, const f16* __restrict__ WoT,
    const float* __restrict__ bo, float* __restrict__ out)
{
    __shared__ __align__(16) f16 ys[64 * 72];
    const int tid = threadIdx.x;
    const int w = tid >> 6, lane = tid & 63;
    const int r = lane & 15, q = lane >> 4;
    const int T0 = blockIdx.x * 64;
    const int bb = T0 >> 12, l0 = T0 & (L_ - 1);
    const int dw = blockIdx.y * 128 + w * 32;

    // stage y transpose: [n-major global] -> ys[t][n]
    {
        const int n = tid & 63, tg = tid >> 6;
        #pragma unroll
        for (int h2 = 0; h2 < 2; h2++) {
            uint4 v = *(const uint4*)&yH[((size_t)(bb * N_ + n)) * L_ + l0 + tg * 16 + h2 * 8];
            const f16* hh = (const f16*)&v;
            #pragma unroll
            for (int j = 0; j < 8; j++)
                ys[(tg * 16 + h2 * 8 + j) * 72 + n] = hh[j];
        }
    }
    __syncthreads();

    f32x4 acc[2][4] = {};
    #pragma unroll
    for (int ks = 0; ks < 2; ks++) {
        const int kk = ks * 32 + q * 8;
        half8 af[2];
        #pragma unroll
        for (int mf = 0; mf < 2; mf++)
            af[mf] = *(const half8*)&WoT[(size_t)(dw + mf * 16 + r) * 64 + kk];
        #pragma unroll
        for (int nf = 0; nf < 4; nf++) {
            half8 bf = *(const half8*)&ys[(nf * 16 + r) * 72 + kk];
            #pragma unroll
            for (int mf = 0; mf < 2; mf++)
                acc[mf][nf] = __builtin_amdgcn_mfma_f32_16x16x32_f16(
                    af[mf], bf, acc[mf][nf], 0, 0, 0);
        }
    }

    #pragma unroll
    for (int mf = 0; mf < 2; mf++) {
        const int d = dw + mf * 16 + q * 4;
        const float4 bb4 = *(const float4*)&bo[d];
        #pragma unroll
        for (int nf = 0; nf < 4; nf++) {
            const int t = T0 + nf * 16 + r;
            float4 o = {acc[mf][nf][0] + bb4.x, acc[mf][nf][1] + bb4.y,
                        acc[mf][nf][2] + bb4.z, acc[mf][nf][3] + bb4.w};
            *(float4*)&out[(size_t)t * D_ + d] = o;
        }
    }
}

// ---------------------------------------------------------------------------
extern "C" void kernel_launch(void* const* d_in, const int* in_sizes, int n_in,
                              void* d_out, int out_size, void* d_ws, size_t ws_size,
                              hipStream_t stream) {
    const float* x      = (const float*)d_in[0];
    const float* conv_w = (const float*)d_in[1];
    const float* conv_b = (const float*)d_in[2];
    const float* Wp     = (const float*)d_in[3];
    const float* bp     = (const float*)d_in[4];
    const float* Ws     = (const float*)d_in[5];
    const float* bs     = (const float*)d_in[6];
    const float* A_log  = (const float*)d_in[7];
    const float* dt_log = (const float*)d_in[8];
    const float* Wo     = (const float*)d_in[9];
    const float* bo     = (const float*)d_in[10];
    float* out = (float*)d_out;

    char* wsp = (char*)d_ws;
    f16* WT  = (f16*)wsp;                     // 384 KB
    f16* WoT = (f16*)(wsp + 393216);          // 128 KB
    f16* zT  = (f16*)(wsp + 524288);          // 2 MB [B,N,L]
    f16* cT  = (f16*)(wsp + 2621440);         // 2 MB
    f16* yH  = (f16*)(wsp + 4718592);         // 2 MB

    k_prepw<<<dim3(128), dim3(256), 0, stream>>>(Wp, Ws, Wo, WT, WoT);
    k_frontend<<<dim3(B_ * L_ / 16), dim3(256), 0, stream>>>(
        x, conv_w, conv_b, WT, bp, bs, dt_log, zT, cT);
    k_scan<<<dim3(B_ * N_), dim3(256), 0, stream>>>(zT, cT, A_log, dt_log, yH);
    k_out<<<dim3(B_ * L_ / 64, D_ / 128), dim3(256), 0, stream>>>(yH, WoT, bo, out);
}

// Round 7
// 187.982 us; speedup vs baseline: 1.0404x; 1.0404x over previous
//
#include <hip/hip_runtime.h>

#define B_ 4
#define L_ 4096
#define D_ 1024
#define N_ 64

typedef _Float16 f16;
typedef __attribute__((ext_vector_type(8))) _Float16 half8;
typedef __attribute__((ext_vector_type(4))) float f32x4;

__device__ __forceinline__ float softplus_f(float x) {
    return fmaxf(x, 0.0f) + log1pf(__expf(-fabsf(x)));
}

__device__ __forceinline__ float tanh_f(float x) {
    float xc = fminf(fmaxf(x, -15.0f), 15.0f);
    float e = __expf(2.0f * xc);
    return (e - 1.0f) / (e + 1.0f);
}

__device__ __forceinline__ void bar_raw() {
    asm volatile("" ::: "memory");
    __builtin_amdgcn_s_barrier();
    asm volatile("" ::: "memory");
}

// ---------------------------------------------------------------------------
// Prep: WT [192][1024] f16 (rows 0-127 = Wp cols, 128-191 = Ws cols);
// WoT [1024][64] f16.  Coalesced reads (lane-consecutive column).
// ---------------------------------------------------------------------------
__global__ __launch_bounds__(256) void k_prepw(
    const float* __restrict__ Wp, const float* __restrict__ Ws,
    const float* __restrict__ Wo, f16* __restrict__ WT, f16* __restrict__ WoT)
{
    int gid = blockIdx.x * 256 + threadIdx.x;
    if (gid < 16384) {                        // Wp: [1024][128]
        int c = gid & 127, kg = gid >> 7;
        f16 h[8];
        #pragma unroll
        for (int j = 0; j < 8; j++)
            h[j] = (f16)Wp[(size_t)(kg * 8 + j) * 128 + c];
        *(uint4*)&WT[(size_t)c * 1024 + kg * 8] = *(uint4*)h;
    } else if (gid < 24576) {                 // Ws: [1024][64]
        int idx = gid - 16384;
        int c = idx & 63, kg = idx >> 6;
        f16 h[8];
        #pragma unroll
        for (int j = 0; j < 8; j++)
            h[j] = (f16)Ws[(size_t)(kg * 8 + j) * 64 + c];
        *(uint4*)&WT[(size_t)(128 + c) * 1024 + kg * 8] = *(uint4*)h;
    } else {                                  // Wo -> WoT [1024][64]
        int idx = gid - 24576;
        int d = idx & 1023, ng = idx >> 10;
        f16 h[8];
        #pragma unroll
        for (int j = 0; j < 8; j++)
            h[j] = (f16)Wo[(size_t)(ng * 8 + j) * D_ + d];
        *(uint4*)&WoT[(size_t)d * 64 + ng * 8] = *(uint4*)h;
    }
}

// ---------------------------------------------------------------------------
// Fused frontend v8: 64 tok/block, 512 thr / 8 waves, grid 256 (1 block/CU).
// True 2-phase double-buffer (guide T3/T4 minimum template):
//   - WT chunk [192][64] f16 staged to LDS ONCE per block per chunk (24KB),
//     double-buffered; all 8 waves read A-frags from LDS (was: each wave
//     re-loading from L2 -> 4x less WT traffic, no 16-line-scatter loads).
//   - Staging is reg-load at chunk top -> swizzled ds_write after MFMA
//     (T14 split); NO __syncthreads in the loop, raw s_barrier + counted
//     compiler vmcnt only -> prefetch spans the whole chunk.
//   - conv computed once per chunk from prefetched x regs into swizzled
//     ch/xh16 LDS; XOR swizzle byte^((row&7)<<4) on all 128B-stride rows.
// Wave (wr,wc) = (w>>2, w&3): 32 tok x 48 cols; 12 MFMA/chunk/wave.
// LDS 64KB: wt0/wt1 24576B each, ch 8192B, xh16 8192B; sE aliases.
// ---------------------------------------------------------------------------
__global__ __launch_bounds__(512, 2) void k_frontend(
    const float* __restrict__ x, const float* __restrict__ conv_w,
    const float* __restrict__ conv_b, const f16* __restrict__ WT,
    const float* __restrict__ bp, const float* __restrict__ bs,
    const float* __restrict__ dt_log,
    f16* __restrict__ zT, f16* __restrict__ cT)
{
    __shared__ __align__(16) char smem[65536];
    char* wt0 = smem;                 // [192][128B] swizzled, chunk buf 0
    char* wt1 = smem + 24576;         // buf 1
    char* chb = smem + 49152;         // [64][128B] swizzled conv
    char* xhb = smem + 57344;         // [64][128B] swizzled raw x (f16)
    float* sE = (float*)smem;         // epilogue alias [3][64][68] f32

    const int tid = threadIdx.x;
    const int w = tid >> 6, lane = tid & 63;
    const int r = lane & 15, q = lane >> 4;
    const int wr = w >> 2, wc = w & 3;
    const int T0 = blockIdx.x * 64;
    const int bb = T0 >> 12, l0 = T0 & (L_ - 1);
    const int cbase = wc * 48;
    const int ct0 = (tid >> 4) * 2;        // 2 tokens per thread
    const int cd  = (tid & 15) * 4;        // 4 dims per thread (in-chunk)

    f32x4 acc[3][2] = {};

    // WT chunk stage: 1536 x 16B slots; slot -> (row=slot>>3, g=slot&7)
    #define WLOAD(RS, c) { _Pragma("unroll") \
        for (int s = 0; s < 3; s++) { \
            int slot = tid + 512 * s; \
            RS[s] = *(const uint4*)&WT[(size_t)(slot >> 3) * 1024 + (c) * 64 + (slot & 7) * 8]; \
        } }
    #define DSWT(BUF, RS) { _Pragma("unroll") \
        for (int s = 0; s < 3; s++) { \
            int slot = tid + 512 * s; int row = slot >> 3, g = slot & 7; \
            *(uint4*)((BUF) + row * 128 + ((g * 16) ^ ((row & 7) << 4))) = RS[s]; \
        } }
    // x rows l0+ct0-3 .. l0+ct0+1 (5) + conv weights/bias for this chunk
    #define XWLOAD(RX, RW, c) { _Pragma("unroll") \
        for (int i = 0; i < 5; i++) { \
            int l = l0 + ct0 - 3 + i; \
            f32x4 v = {0.f, 0.f, 0.f, 0.f}; \
            if (l >= 0) v = *(const f32x4*)&x[((size_t)(bb * L_ + l)) * D_ + (c) * 64 + cd]; \
            RX[i] = v; } \
        _Pragma("unroll") \
        for (int k = 0; k < 4; k++) \
            RW[k] = *(const f32x4*)&conv_w[k * D_ + (c) * 64 + cd]; \
        RW[4] = *(const f32x4*)&conv_b[(c) * 64 + cd]; }

    #define CONV(RX, RW) { _Pragma("unroll") \
        for (int tt = 0; tt < 2; tt++) { \
            const int t = ct0 + tt; \
            f16 hc4[4], hx4[4]; \
            _Pragma("unroll") \
            for (int j = 0; j < 4; j++) { \
                float s0 = RW[4][j]; \
                s0 = fmaf(RW[0][j], RX[tt + 0][j], s0); \
                s0 = fmaf(RW[1][j], RX[tt + 1][j], s0); \
                s0 = fmaf(RW[2][j], RX[tt + 2][j], s0); \
                s0 = fmaf(RW[3][j], RX[tt + 3][j], s0); \
                hc4[j] = (f16)s0; hx4[j] = (f16)RX[tt + 3][j]; \
            } \
            const int cb = (cd * 2) ^ ((t & 7) << 4); \
            *(uint2*)(chb + t * 128 + cb) = *(uint2*)hc4; \
            *(uint2*)(xhb + t * 128 + cb) = *(uint2*)hx4; \
        } }

    #define MFMA_PH(WTC) { \
        const bool nC = (cbase < 128); \
        const bool nX = (cbase + 32 >= 128); \
        _Pragma("unroll") \
        for (int ks = 0; ks < 2; ks++) { \
            const int cb16 = ks * 64 + q * 16; \
            half8 a8[3]; \
            _Pragma("unroll") \
            for (int mf = 0; mf < 3; mf++) { \
                const int ar = cbase + mf * 16 + r; \
                a8[mf] = *(const half8*)((WTC) + ar * 128 + (cb16 ^ ((ar & 7) << 4))); \
            } \
            _Pragma("unroll") \
            for (int nf = 0; nf < 2; nf++) { \
                const int tr = wr * 32 + nf * 16 + r; \
                const int tb = cb16 ^ ((tr & 7) << 4); \
                half8 bc = {}, bx = {}; \
                if (nC) bc = *(const half8*)(chb + tr * 128 + tb); \
                if (nX) bx = *(const half8*)(xhb + tr * 128 + tb); \
                acc[0][nf] = __builtin_amdgcn_mfma_f32_16x16x32_f16( \
                    a8[0], (cbase < 128) ? bc : bx, acc[0][nf], 0, 0, 0); \
                acc[1][nf] = __builtin_amdgcn_mfma_f32_16x16x32_f16( \
                    a8[1], (cbase + 16 < 128) ? bc : bx, acc[1][nf], 0, 0, 0); \
                acc[2][nf] = __builtin_amdgcn_mfma_f32_16x16x32_f16( \
                    a8[2], (cbase + 32 < 128) ? bc : bx, acc[2][nf], 0, 0, 0); \
            } \
        } }

    // One chunk: prefetch(c+1) -> conv(c) -> [lgkm0+SB+bar] -> MFMA(c)
    // -> ds_write WT(c+1) -> raw bar.  No vmcnt(0) anywhere in the loop.
    #define CHUNK(c, RX, RW, RSN, RXN, RWN, WTC, WTN, PF) { \
        if (PF) { WLOAD(RSN, (c) + 1); XWLOAD(RXN, RWN, (c) + 1); } \
        CONV(RX, RW); \
        asm volatile("s_waitcnt lgkmcnt(0)" ::: "memory"); \
        __builtin_amdgcn_sched_barrier(0); \
        __builtin_amdgcn_s_barrier(); \
        asm volatile("" ::: "memory"); \
        MFMA_PH(WTC); \
        if (PF) { DSWT(WTN, RSN); } \
        bar_raw(); }

    f32x4 rXa[5], rWa[5], rXb[5], rWb[5];
    uint4 rSa[3], rSb[3];

    // prologue: chunk 0 staged + x/cw regs for chunk 0
    WLOAD(rSa, 0);
    XWLOAD(rXa, rWa, 0);
    DSWT(wt0, rSa);
    __syncthreads();

    #pragma unroll 1
    for (int cc = 0; cc < 8; cc++) {
        const int c0 = cc * 2;
        CHUNK(c0,     rXa, rWa, rSb, rXb, rWb, wt0, wt1, true);
        CHUNK(c0 + 1, rXb, rWb, rSa, rXa, rWa, wt1, wt0, (c0 + 1) < 15);
    }

    // --- epilogue: bias + activation -> sE (aliases wt/ch LDS) ---
    float* sB = sE;
    float* sC = sE + 64 * 68;
    float* sU = sE + 2 * 64 * 68;
    #pragma unroll
    for (int mf = 0; mf < 3; mf++) {
        const int cb4 = cbase + mf * 16 + q * 4;
        const int seg = cb4 >> 6;          // 0=Bt 1=Ct 2=u (frag-uniform)
        const int cl = cb4 & 63;
        const float4 bb4 = (seg == 2) ? *(const float4*)&bs[cl]
                                      : *(const float4*)&bp[cb4];
        float* dst = (seg == 0) ? sB : (seg == 1 ? sC : sU);
        #pragma unroll
        for (int nf = 0; nf < 2; nf++) {
            const int t = wr * 32 + nf * 16 + r;
            float v0 = acc[mf][nf][0] + bb4.x;
            float v1 = acc[mf][nf][1] + bb4.y;
            float v2 = acc[mf][nf][2] + bb4.z;
            float v3 = acc[mf][nf][3] + bb4.w;
            if (seg == 0) {
                v0 = softplus_f(v0); v1 = softplus_f(v1);
                v2 = softplus_f(v2); v3 = softplus_f(v3);
            } else if (seg == 1) {
                v0 = tanh_f(v0); v1 = tanh_f(v1);
                v2 = tanh_f(v2); v3 = tanh_f(v3);
            }
            float4 vv = {v0, v1, v2, v3};
            *(float4*)&dst[t * 68 + cl] = vv;
        }
    }
    __syncthreads();

    // --- fused combine: z = dt[n]*Bt*u, store zT/cT n-major ---
    {
        const int n = tid >> 3, tg = tid & 7;
        const float dtv = softplus_f(dt_log[n]);
        f16 hz[8], hc2[8];
        #pragma unroll
        for (int j = 0; j < 8; j++) {
            const int t = tg * 8 + j;
            hz[j] = (f16)(dtv * sB[t * 68 + n] * sU[t * 68 + n]);
            hc2[j] = (f16)sC[t * 68 + n];
        }
        size_t o = ((size_t)(bb * N_ + n)) * L_ + l0 + tg * 8;
        *(uint4*)&zT[o] = *(uint4*)hz;
        *(uint4*)&cT[o] = *(uint4*)hc2;
    }
    #undef WLOAD
    #undef DSWT
    #undef XWLOAD
    #undef CONV
    #undef MFMA_PH
    #undef CHUNK
}

// ---------------------------------------------------------------------------
// Scan v2: 256 threads per (b,n) chain.  Thread t owns elems [16t,16t+16);
// serial 16-fma local reduce -> 64-lane shfl affine scan -> cross-wave
// stitch via LDS -> apply.  +i>>4 swizzle avoids 32-way bank conflicts.
// ---------------------------------------------------------------------------
#define ZI(i) ((i) + ((i) >> 4))
__global__ __launch_bounds__(256) void k_scan(
    const f16* __restrict__ zT, const f16* __restrict__ cT,
    const float* __restrict__ A_log, const float* __restrict__ dt_log,
    f16* __restrict__ yH)
{
    __shared__ float zs[4352];
    __shared__ float cs[4352];
    __shared__ float sA[4], sB[4];
    const int bn = blockIdx.x;
    const int n = bn & (N_ - 1);
    const int tid = threadIdx.x;
    const int lane = tid & 63, w = tid >> 6;
    const f16* zp = zT + (size_t)bn * L_;
    const f16* cp = cT + (size_t)bn * L_;

    #pragma unroll
    for (int it = 0; it < 2; it++) {
        int i = tid * 8 + it * 2048;
        uint4 rz = *(const uint4*)(zp + i);
        uint4 rc = *(const uint4*)(cp + i);
        const f16* hz = (const f16*)&rz;
        const f16* hc = (const f16*)&rc;
        #pragma unroll
        for (int k = 0; k < 8; k++) {
            zs[ZI(i + k)] = (float)hz[k];
            cs[ZI(i + k)] = (float)hc[k];
        }
    }
    __syncthreads();

    float dtv = softplus_f(dt_log[n]);
    float Av = -softplus_f(A_log[n]);
    float dec = fmaf(dtv, Av, 1.0f);

    const int base = tid * 17;           // ZI(tid*16)
    float s = 0.0f;
    #pragma unroll
    for (int j = 0; j < 16; j++) s = fmaf(dec, s, zs[base + j]);

    float d2 = dec * dec, d4 = d2 * d2, d8 = d4 * d4, d16 = d8 * d8;

    float Ag = d16, Bg = s;
    #pragma unroll
    for (int off = 1; off < 64; off <<= 1) {
        float Ap = __shfl_up(Ag, off);
        float Bp = __shfl_up(Bg, off);
        if (lane >= off) { Bg = fmaf(Ag, Bp, Bg); Ag *= Ap; }
    }
    if (lane == 63) { sA[w] = Ag; sB[w] = Bg; }
    __syncthreads();

    float Bc = 0.0f;                      // carry entering this wave
    for (int i = 0; i < w; i++) Bc = fmaf(sA[i], Bc, sB[i]);
    float Ae = __shfl_up(Ag, 1);          // exclusive within wave
    float Be = __shfl_up(Bg, 1);
    if (lane == 0) { Ae = 1.0f; Be = 0.0f; }
    float carry = fmaf(Ae, Bc, Be);       // state entering this thread

    float st = carry;
    #pragma unroll
    for (int j = 0; j < 16; j++) {
        st = fmaf(dec, st, zs[base + j]);
        zs[base + j] = cs[base + j] * st;
    }
    __syncthreads();

    f16* yp = yH + (size_t)bn * L_;
    #pragma unroll
    for (int it = 0; it < 2; it++) {
        int i = tid * 8 + it * 2048;
        f16 h[8];
        #pragma unroll
        for (int k = 0; k < 8; k++) h[k] = (f16)zs[ZI(i + k)];
        *(uint4*)&yp[i] = *(uint4*)h;
    }
}
#undef ZI

// ---------------------------------------------------------------------------
// Out GEMM: out[t][d] = y[t][:] @ Wo[:,d] + bo.  A = WoT (m=d), B = y (n=tok)
// Block 256 thr: 64 tok x 128 d, wave = 32 d x 64 tok.  Grid (256, 8).
// ---------------------------------------------------------------------------
__global__ __launch_bounds__(256) void k_out(
    const f16* __restrict__ yH, const f16* __restrict__ WoT,
    const float* __restrict__ bo, float* __restrict__ out)
{
    __shared__ __align__(16) f16 ys[64 * 72];
    const int tid = threadIdx.x;
    const int w = tid >> 6, lane = tid & 63;
    const int r = lane & 15, q = lane >> 4;
    const int T0 = blockIdx.x * 64;
    const int bb = T0 >> 12, l0 = T0 & (L_ - 1);
    const int dw = blockIdx.y * 128 + w * 32;

    // stage y transpose: [n-major global] -> ys[t][n]
    {
        const int n = tid & 63, tg = tid >> 6;
        #pragma unroll
        for (int h2 = 0; h2 < 2; h2++) {
            uint4 v = *(const uint4*)&yH[((size_t)(bb * N_ + n)) * L_ + l0 + tg * 16 + h2 * 8];
            const f16* hh = (const f16*)&v;
            #pragma unroll
            for (int j = 0; j < 8; j++)
                ys[(tg * 16 + h2 * 8 + j) * 72 + n] = hh[j];
        }
    }
    __syncthreads();

    f32x4 acc[2][4] = {};
    #pragma unroll
    for (int ks = 0; ks < 2; ks++) {
        const int kk = ks * 32 + q * 8;
        half8 af[2];
        #pragma unroll
        for (int mf = 0; mf < 2; mf++)
            af[mf] = *(const half8*)&WoT[(size_t)(dw + mf * 16 + r) * 64 + kk];
        #pragma unroll
        for (int nf = 0; nf < 4; nf++) {
            half8 bf = *(const half8*)&ys[(nf * 16 + r) * 72 + kk];
            #pragma unroll
            for (int mf = 0; mf < 2; mf++)
                acc[mf][nf] = __builtin_amdgcn_mfma_f32_16x16x32_f16(
                    af[mf], bf, acc[mf][nf], 0, 0, 0);
        }
    }

    #pragma unroll
    for (int mf = 0; mf < 2; mf++) {
        const int d = dw + mf * 16 + q * 4;
        const float4 bb4 = *(const float4*)&bo[d];
        #pragma unroll
        for (int nf = 0; nf < 4; nf++) {
            const int t = T0 + nf * 16 + r;
            float4 o = {acc[mf][nf][0] + bb4.x, acc[mf][nf][1] + bb4.y,
                        acc[mf][nf][2] + bb4.z, acc[mf][nf][3] + bb4.w};
            *(float4*)&out[(size_t)t * D_ + d] = o;
        }
    }
}

// ---------------------------------------------------------------------------
extern "C" void kernel_launch(void* const* d_in, const int* in_sizes, int n_in,
                              void* d_out, int out_size, void* d_ws, size_t ws_size,
                              hipStream_t stream) {
    const float* x      = (const float*)d_in[0];
    const float* conv_w = (const float*)d_in[1];
    const float* conv_b = (const float*)d_in[2];
    const float* Wp     = (const float*)d_in[3];
    const float* bp     = (const float*)d_in[4];
    const float* Ws     = (const float*)d_in[5];
    const float* bs     = (const float*)d_in[6];
    const float* A_log  = (const float*)d_in[7];
    const float* dt_log = (const float*)d_in[8];
    const float* Wo     = (const float*)d_in[9];
    const float* bo     = (const float*)d_in[10];
    float* out = (float*)d_out;

    char* wsp = (char*)d_ws;
    f16* WT  = (f16*)wsp;                     // 384 KB
    f16* WoT = (f16*)(wsp + 393216);          // 128 KB
    f16* zT  = (f16*)(wsp + 524288);          // 2 MB [B,N,L]
    f16* cT  = (f16*)(wsp + 2621440);         // 2 MB
    f16* yH  = (f16*)(wsp + 4718592);         // 2 MB

    k_prepw<<<dim3(128), dim3(256), 0, stream>>>(Wp, Ws, Wo, WT, WoT);
    k_frontend<<<dim3(B_ * L_ / 64), dim3(512), 0, stream>>>(
        x, conv_w, conv_b, WT, bp, bs, dt_log, zT, cT);
    k_scan<<<dim3(B_ * N_), dim3(256), 0, stream>>>(zT, cT, A_log, dt_log, yH);
    k_out<<<dim3(B_ * L_ / 64, D_ / 128), dim3(256), 0, stream>>>(yH, WoT, bo, out);
}